// Round 2
// baseline (261.150 us; speedup 1.0000x reference)
//
#include <hip/hip_runtime.h>

// Plenoxels: trilinear voxel interp (192^3 x 28 ch) + SH deg-2 eval.
// R2: stream compaction. Only ~16.3% of points pass the mask; R1 paid full
// gather issue+latency in every wave with ~10/64 lanes active. Now:
//   K0: zero worklist counter (in d_ws)
//   K1: zero all outputs (coalesced float4), compute mask, wave-aggregated
//       atomic append of active indices to worklist
//   K2: grid-stride over worklist -> gather + SH with full waves
// Falls back to the validated R1 single-kernel if ws_size is insufficient.

#define VNL 192

// ---------------- shared device math (exact R1 semantics, validated) --------
__device__ __forceinline__ void plen_point(
    int i, float px, float py, float pz,
    const float* __restrict__ d, const float* __restrict__ voxel,
    float* __restrict__ out, int N)
{
    const float SH_C0 = 0.28209479177387814f;
    const float SH_C1 = 0.4886025119029199f;
    const float C2_0 =  1.0925484305920792f;
    const float C2_1 = -1.0925484305920792f;
    const float C2_2 =  0.31539156525252005f;
    const float C2_3 = -1.0925484305920792f;
    const float C2_4 =  0.5462742152960396f;

    const float step = 2.0f / (float)VNL;
    float ix = fminf(fmaxf(px / step + (float)(VNL / 2), 0.0f), (float)(VNL - 1));
    float iy = fminf(fmaxf(py / step + (float)(VNL / 2), 0.0f), (float)(VNL - 1));
    float iz = fminf(fmaxf(pz / step + (float)(VNL / 2), 0.0f), (float)(VNL - 1));

    float fx = floorf(ix), fy = floorf(iy), fz = floorf(iz);
    int f0 = (int)fx, f1 = (int)fy, f2 = (int)fz;
    int c0 = (int)ceilf(ix), c1 = (int)ceilf(iy), c2 = (int)ceilf(iz);

    float t0 = ix - fx, t1 = iy - fy, t2 = iz - fz;
    float u0 = 1.0f - t0, u1 = 1.0f - t1, u2 = 1.0f - t2;

    // EXACT reference corner order and (non-standard) weight pairing:
    float w[8]  = { u2*u1*u0, u2*u1*t0, u2*t1*u0, u2*t1*t0,
                    t2*u1*u0, t2*u1*t0, t2*t1*u0, t2*t1*t0 };
    int  cx[8]  = { f0, c0, f0, f0, f0, c0, c0, c0 };
    int  cy[8]  = { f1, f1, c1, f1, c1, f1, c1, c1 };
    int  cz[8]  = { f2, f2, f2, c2, c2, c2, f2, c2 };

    float feat[28];
    #pragma unroll
    for (int c = 0; c < 28; ++c) feat[c] = 0.0f;

    #pragma unroll
    for (int j = 0; j < 8; ++j) {
        size_t base = ((size_t)(cx[j] * VNL + cy[j]) * VNL + cz[j]) * 28;
        const float4* vp = reinterpret_cast<const float4*>(voxel + base); // 112B cells, 16B aligned
        float wj = w[j];
        #pragma unroll
        for (int q = 0; q < 7; ++q) {
            float4 v4 = vp[q];
            feat[4 * q + 0] += wj * v4.x;
            feat[4 * q + 1] += wj * v4.y;
            feat[4 * q + 2] += wj * v4.z;
            feat[4 * q + 3] += wj * v4.w;
        }
    }

    float sig = fmaxf(feat[0], 0.0f);

    float dx = d[3 * i + 0], dy = d[3 * i + 1], dz = d[3 * i + 2];
    float xy = dx * dy, yz = dy * dz, xz = dx * dz;
    float zsq = 2.0f * dz * dz - dx * dx - dy * dy;
    float xmy = dx * dx - dy * dy;

    float cols[3];
    #pragma unroll
    for (int ch = 0; ch < 3; ++ch) {
        const int b = 1 + 9 * ch;
        cols[ch] = SH_C0 * feat[b + 0]
                 - SH_C1 * dy * feat[b + 1]
                 + SH_C1 * dz * feat[b + 2]
                 - SH_C1 * dx * feat[b + 3]
                 + C2_0 * xy  * feat[b + 4]
                 + C2_1 * yz  * feat[b + 5]
                 + C2_2 * zsq * feat[b + 6]
                 + C2_3 * xz  * feat[b + 7]
                 + C2_4 * xmy * feat[b + 8];
    }

    out[3 * i + 0] = cols[0];
    out[3 * i + 1] = cols[1];
    out[3 * i + 2] = cols[2];
    out[(size_t)3 * N + i] = sig;
}

// ---------------- K0: zero the worklist counter -----------------------------
__global__ void zero_counter_kernel(unsigned* __restrict__ cnt) {
    *cnt = 0;
}

// ---------------- K1: zero outputs + mask + compact -------------------------
__global__ __launch_bounds__(256) void mask_compact_kernel(
    const float* __restrict__ x,
    float* __restrict__ out,          // 4N floats, zeroed here
    unsigned* __restrict__ cnt,
    int* __restrict__ wl,
    int N)
{
    int i = blockIdx.x * 256 + threadIdx.x;

    bool act = false;
    if (i < N) {
        // out has 4N floats; thread i zeroes float4 #i -> covers all of out.
        reinterpret_cast<float4*>(out)[i] = make_float4(0.f, 0.f, 0.f, 0.f);

        float px = x[3 * i + 0] / 1.5f;
        float py = x[3 * i + 1] / 1.5f;
        float pz = x[3 * i + 2] / 1.5f;
        act = (fabsf(px) < 0.5f) && (fabsf(py) < 0.5f) && (fabsf(pz) < 0.5f);
    }

    // Wave-aggregated append (one atomic per wave).
    unsigned long long b = __ballot(act);
    int lane = threadIdx.x & 63;
    unsigned wtot = (unsigned)__popcll(b);
    unsigned pre  = (unsigned)__popcll(b & ((1ull << lane) - 1ull));
    int base = 0;
    if (lane == 0 && wtot > 0) base = (int)atomicAdd(cnt, wtot);
    base = __shfl(base, 0, 64);
    if (act) wl[base + (int)pre] = i;
}

// ---------------- K2: gather + SH over compacted worklist -------------------
__global__ __launch_bounds__(256) void gather_kernel(
    const float* __restrict__ x,
    const float* __restrict__ d,
    const float* __restrict__ voxel,
    float* __restrict__ out,
    const unsigned* __restrict__ cnt,
    const int* __restrict__ wl,
    int N)
{
    int cn = (int)*cnt;
    for (int t = blockIdx.x * 256 + threadIdx.x; t < cn; t += gridDim.x * 256) {
        int i = wl[t];
        float px = x[3 * i + 0] / 1.5f;
        float py = x[3 * i + 1] / 1.5f;
        float pz = x[3 * i + 2] / 1.5f;
        plen_point(i, px, py, pz, d, voxel, out, N);
    }
}

// ---------------- fallback: validated R1 single-kernel ----------------------
__global__ __launch_bounds__(256) void plen_single_kernel(
    const float* __restrict__ x,
    const float* __restrict__ d,
    const float* __restrict__ voxel,
    float* __restrict__ out,
    int N)
{
    int i = blockIdx.x * blockDim.x + threadIdx.x;
    if (i >= N) return;

    float px = x[3 * i + 0] / 1.5f;
    float py = x[3 * i + 1] / 1.5f;
    float pz = x[3 * i + 2] / 1.5f;
    bool mask = (fabsf(px) < 0.5f) && (fabsf(py) < 0.5f) && (fabsf(pz) < 0.5f);

    if (mask) {
        plen_point(i, px, py, pz, d, voxel, out, N);
    } else {
        out[3 * i + 0] = 0.0f;
        out[3 * i + 1] = 0.0f;
        out[3 * i + 2] = 0.0f;
        out[(size_t)3 * N + i] = 0.0f;
    }
}

extern "C" void kernel_launch(void* const* d_in, const int* in_sizes, int n_in,
                              void* d_out, int out_size, void* d_ws, size_t ws_size,
                              hipStream_t stream) {
    const float* x     = (const float*)d_in[0];
    const float* d     = (const float*)d_in[1];
    const float* voxel = (const float*)d_in[2];
    float* out = (float*)d_out;
    int N = in_sizes[0] / 3;

    size_t need = 256 + (size_t)N * sizeof(int);
    if (ws_size >= need) {
        unsigned* cnt = (unsigned*)d_ws;
        int* wl = (int*)((char*)d_ws + 256);

        zero_counter_kernel<<<1, 1, 0, stream>>>(cnt);
        int grid1 = (N + 255) / 256;
        mask_compact_kernel<<<grid1, 256, 0, stream>>>(x, out, cnt, wl, N);
        int grid2 = 1024;  // grid-stride covers any count
        gather_kernel<<<grid2, 256, 0, stream>>>(x, d, voxel, out, cnt, wl, N);
    } else {
        int grid = (N + 255) / 256;
        plen_single_kernel<<<grid, 256, 0, stream>>>(x, d, voxel, out, N);
    }
}

// Round 3
// 89.093 us; speedup vs baseline: 2.9312x; 2.9312x over previous
//
#include <hip/hip_runtime.h>

// Plenoxels: trilinear voxel interp (192^3 x 28 ch) + SH deg-2 eval.
// R3: compaction retained but fixed:
//  - K1 aggregates the worklist append at BLOCK level (1 atomic / 1024 thr)
//  - worklist entries pack (px,py,pz,idx, dx,dy,dz) -> K2 reads 2 coalesced float4
//  - K2 grid = 2048 blocks (32 waves/CU) grid-stride
// Fallback to validated R1 single-kernel if ws too small.

#define VNL 192
#define K1_BLK 1024
#define K2_GRID 2048

// ---------------- core math on one active point -----------------------------
__device__ __forceinline__ void plen_core(
    int i, float px, float py, float pz,
    float dx, float dy, float dz,
    const float* __restrict__ voxel,
    float* __restrict__ out, int N)
{
    const float SH_C0 = 0.28209479177387814f;
    const float SH_C1 = 0.4886025119029199f;
    const float C2_0 =  1.0925484305920792f;
    const float C2_1 = -1.0925484305920792f;
    const float C2_2 =  0.31539156525252005f;
    const float C2_3 = -1.0925484305920792f;
    const float C2_4 =  0.5462742152960396f;

    const float step = 2.0f / (float)VNL;
    float ix = fminf(fmaxf(px / step + (float)(VNL / 2), 0.0f), (float)(VNL - 1));
    float iy = fminf(fmaxf(py / step + (float)(VNL / 2), 0.0f), (float)(VNL - 1));
    float iz = fminf(fmaxf(pz / step + (float)(VNL / 2), 0.0f), (float)(VNL - 1));

    float fx = floorf(ix), fy = floorf(iy), fz = floorf(iz);
    int f0 = (int)fx, f1 = (int)fy, f2 = (int)fz;
    int c0 = (int)ceilf(ix), c1 = (int)ceilf(iy), c2 = (int)ceilf(iz);

    float t0 = ix - fx, t1 = iy - fy, t2 = iz - fz;
    float u0 = 1.0f - t0, u1 = 1.0f - t1, u2 = 1.0f - t2;

    // EXACT reference corner order and (non-standard) weight pairing:
    float w[8]  = { u2*u1*u0, u2*u1*t0, u2*t1*u0, u2*t1*t0,
                    t2*u1*u0, t2*u1*t0, t2*t1*u0, t2*t1*t0 };
    int  cx[8]  = { f0, c0, f0, f0, f0, c0, c0, c0 };
    int  cy[8]  = { f1, f1, c1, f1, c1, f1, c1, c1 };
    int  cz[8]  = { f2, f2, f2, c2, c2, c2, f2, c2 };

    float feat[28];
    #pragma unroll
    for (int c = 0; c < 28; ++c) feat[c] = 0.0f;

    #pragma unroll
    for (int j = 0; j < 8; ++j) {
        size_t base = ((size_t)(cx[j] * VNL + cy[j]) * VNL + cz[j]) * 28;
        const float4* vp = reinterpret_cast<const float4*>(voxel + base); // 112B cells, 16B aligned
        float wj = w[j];
        #pragma unroll
        for (int q = 0; q < 7; ++q) {
            float4 v4 = vp[q];
            feat[4 * q + 0] += wj * v4.x;
            feat[4 * q + 1] += wj * v4.y;
            feat[4 * q + 2] += wj * v4.z;
            feat[4 * q + 3] += wj * v4.w;
        }
    }

    float sig = fmaxf(feat[0], 0.0f);

    float xy = dx * dy, yz = dy * dz, xz = dx * dz;
    float zsq = 2.0f * dz * dz - dx * dx - dy * dy;
    float xmy = dx * dx - dy * dy;

    float cols[3];
    #pragma unroll
    for (int ch = 0; ch < 3; ++ch) {
        const int b = 1 + 9 * ch;
        cols[ch] = SH_C0 * feat[b + 0]
                 - SH_C1 * dy * feat[b + 1]
                 + SH_C1 * dz * feat[b + 2]
                 - SH_C1 * dx * feat[b + 3]
                 + C2_0 * xy  * feat[b + 4]
                 + C2_1 * yz  * feat[b + 5]
                 + C2_2 * zsq * feat[b + 6]
                 + C2_3 * xz  * feat[b + 7]
                 + C2_4 * xmy * feat[b + 8];
    }

    out[3 * i + 0] = cols[0];
    out[3 * i + 1] = cols[1];
    out[3 * i + 2] = cols[2];
    out[(size_t)3 * N + i] = sig;
}

// ---------------- K0: zero the worklist counter -----------------------------
__global__ void zero_counter_kernel(unsigned* __restrict__ cnt) {
    *cnt = 0;
}

// ---------------- K1: zero outputs + mask + block-aggregated compact --------
__global__ __launch_bounds__(K1_BLK) void mask_compact_kernel(
    const float* __restrict__ x,
    const float* __restrict__ d,
    float* __restrict__ out,          // 4N floats, zeroed here
    unsigned* __restrict__ cnt,
    float4* __restrict__ wl,          // 2 float4 per entry
    int N)
{
    __shared__ unsigned s_wcnt[K1_BLK / 64];
    __shared__ unsigned s_base;

    int i = blockIdx.x * K1_BLK + threadIdx.x;
    int wid  = threadIdx.x >> 6;
    int lane = threadIdx.x & 63;

    bool act = false;
    float px = 0.f, py = 0.f, pz = 0.f;
    if (i < N) {
        // out has 4N floats; thread i zeroes float4 #i -> covers all of out.
        reinterpret_cast<float4*>(out)[i] = make_float4(0.f, 0.f, 0.f, 0.f);

        px = x[3 * i + 0] / 1.5f;
        py = x[3 * i + 1] / 1.5f;
        pz = x[3 * i + 2] / 1.5f;
        act = (fabsf(px) < 0.5f) && (fabsf(py) < 0.5f) && (fabsf(pz) < 0.5f);
    }

    unsigned long long b = __ballot(act);
    unsigned wtot = (unsigned)__popcll(b);
    unsigned pre  = (unsigned)__popcll(b & ((1ull << lane) - 1ull));

    if (lane == 0) s_wcnt[wid] = wtot;
    __syncthreads();
    if (threadIdx.x == 0) {
        unsigned tot = 0;
        #pragma unroll
        for (int ww = 0; ww < K1_BLK / 64; ++ww) tot += s_wcnt[ww];
        s_base = (tot > 0) ? atomicAdd(cnt, tot) : 0u;  // ONE atomic per block
    }
    __syncthreads();

    if (act) {
        unsigned off = s_base;
        for (int ww = 0; ww < wid; ++ww) off += s_wcnt[ww];
        unsigned slot = off + pre;
        float dx = d[3 * i + 0], dy = d[3 * i + 1], dz = d[3 * i + 2];
        wl[2 * (size_t)slot + 0] = make_float4(px, py, pz, __int_as_float(i));
        wl[2 * (size_t)slot + 1] = make_float4(dx, dy, dz, 0.f);
    }
}

// ---------------- K2: gather + SH over compacted worklist -------------------
__global__ __launch_bounds__(256) void gather_kernel(
    const float* __restrict__ voxel,
    float* __restrict__ out,
    const unsigned* __restrict__ cnt,
    const float4* __restrict__ wl,
    int N)
{
    int cn = (int)*cnt;
    for (int t = blockIdx.x * 256 + threadIdx.x; t < cn; t += K2_GRID * 256) {
        float4 e0 = wl[2 * (size_t)t + 0];
        float4 e1 = wl[2 * (size_t)t + 1];
        int i = __float_as_int(e0.w);
        plen_core(i, e0.x, e0.y, e0.z, e1.x, e1.y, e1.z, voxel, out, N);
    }
}

// ---------------- fallback: validated R1 single-kernel ----------------------
__global__ __launch_bounds__(256) void plen_single_kernel(
    const float* __restrict__ x,
    const float* __restrict__ d,
    const float* __restrict__ voxel,
    float* __restrict__ out,
    int N)
{
    int i = blockIdx.x * blockDim.x + threadIdx.x;
    if (i >= N) return;

    float px = x[3 * i + 0] / 1.5f;
    float py = x[3 * i + 1] / 1.5f;
    float pz = x[3 * i + 2] / 1.5f;
    bool mask = (fabsf(px) < 0.5f) && (fabsf(py) < 0.5f) && (fabsf(pz) < 0.5f);

    if (mask) {
        float dx = d[3 * i + 0], dy = d[3 * i + 1], dz = d[3 * i + 2];
        plen_core(i, px, py, pz, dx, dy, dz, voxel, out, N);
    } else {
        out[3 * i + 0] = 0.0f;
        out[3 * i + 1] = 0.0f;
        out[3 * i + 2] = 0.0f;
        out[(size_t)3 * N + i] = 0.0f;
    }
}

extern "C" void kernel_launch(void* const* d_in, const int* in_sizes, int n_in,
                              void* d_out, int out_size, void* d_ws, size_t ws_size,
                              hipStream_t stream) {
    const float* x     = (const float*)d_in[0];
    const float* d     = (const float*)d_in[1];
    const float* voxel = (const float*)d_in[2];
    float* out = (float*)d_out;
    int N = in_sizes[0] / 3;

    size_t need = 256 + (size_t)N * 32;
    if (ws_size >= need) {
        unsigned* cnt = (unsigned*)d_ws;
        float4* wl = (float4*)((char*)d_ws + 256);

        zero_counter_kernel<<<1, 1, 0, stream>>>(cnt);
        int grid1 = (N + K1_BLK - 1) / K1_BLK;
        mask_compact_kernel<<<grid1, K1_BLK, 0, stream>>>(x, d, out, cnt, wl, N);
        gather_kernel<<<K2_GRID, 256, 0, stream>>>(voxel, out, cnt, wl, N);
    } else {
        int grid = (N + 255) / 256;
        plen_single_kernel<<<grid, 256, 0, stream>>>(x, d, voxel, out, N);
    }
}

// Round 4
// 72.103 us; speedup vs baseline: 3.6219x; 1.2356x over previous
//
#include <hip/hip_runtime.h>

// Plenoxels: trilinear voxel interp (192^3 x 28 ch) + SH deg-2 eval.
// R4: wave-cooperative gather. R1 (masked lanes) == R3 (compacted full lanes)
// at ~87us -> bottleneck is per-point load-instruction/probe structure, not
// lane util. Now ONE WAVE gathers one point's 8*112B in ONE dwordx4 instr:
//   lane = corner*8 + quad; TA merges same-line lanes (z-adjacent corners are
//   contiguous 224B runs). Corner-sum via shfl_xor butterfly; SH by lanes 0-3.
// K1 precomputes per-point (i,d, w[8], byteoff[8]) so K2 does no index math.

#define VNL 192
#define K1_BLK 1024
#define K2_GRID 2048
#define K2_BLK 256
#define K2_WPB (K2_BLK / 64)
#define K2_WAVES (K2_GRID * K2_WPB)

#define SH_C0f 0.28209479177387814f
#define SH_C1f 0.4886025119029199f
#define C2_0f  1.0925484305920792f
#define C2_1f (-1.0925484305920792f)
#define C2_2f  0.31539156525252005f
#define C2_3f (-1.0925484305920792f)
#define C2_4f  0.5462742152960396f

// ---------------- K0: zero the worklist counter -----------------------------
__global__ void zero_counter_kernel(unsigned* __restrict__ cnt) {
    *cnt = 0;
}

// ---------------- K1: zero out + mask + expand to 80B records ---------------
__global__ __launch_bounds__(K1_BLK) void mask_expand_kernel(
    const float* __restrict__ x,
    const float* __restrict__ d,
    float* __restrict__ out,          // 4N floats, zeroed here
    unsigned* __restrict__ cnt,
    float4* __restrict__ wl,          // 5 float4 per record
    int N)
{
    __shared__ unsigned s_wcnt[K1_BLK / 64];
    __shared__ unsigned s_base;

    int i = blockIdx.x * K1_BLK + threadIdx.x;
    int wid  = threadIdx.x >> 6;
    int lane = threadIdx.x & 63;

    bool act = false;
    float px = 0.f, py = 0.f, pz = 0.f;
    if (i < N) {
        reinterpret_cast<float4*>(out)[i] = make_float4(0.f, 0.f, 0.f, 0.f);
        px = x[3 * i + 0] / 1.5f;
        py = x[3 * i + 1] / 1.5f;
        pz = x[3 * i + 2] / 1.5f;
        act = (fabsf(px) < 0.5f) && (fabsf(py) < 0.5f) && (fabsf(pz) < 0.5f);
    }

    unsigned long long b = __ballot(act);
    unsigned wtot = (unsigned)__popcll(b);
    unsigned pre  = (unsigned)__popcll(b & ((1ull << lane) - 1ull));

    if (lane == 0) s_wcnt[wid] = wtot;
    __syncthreads();
    if (threadIdx.x == 0) {
        unsigned tot = 0;
        #pragma unroll
        for (int ww = 0; ww < K1_BLK / 64; ++ww) tot += s_wcnt[ww];
        s_base = (tot > 0) ? atomicAdd(cnt, tot) : 0u;  // ONE atomic per block
    }
    __syncthreads();

    if (act) {
        unsigned off = s_base;
        for (int ww = 0; ww < wid; ++ww) off += s_wcnt[ww];
        unsigned slot = off + pre;

        const float step = 2.0f / (float)VNL;
        float ix = fminf(fmaxf(px / step + (float)(VNL / 2), 0.0f), (float)(VNL - 1));
        float iy = fminf(fmaxf(py / step + (float)(VNL / 2), 0.0f), (float)(VNL - 1));
        float iz = fminf(fmaxf(pz / step + (float)(VNL / 2), 0.0f), (float)(VNL - 1));

        float fx = floorf(ix), fy = floorf(iy), fz = floorf(iz);
        int f0 = (int)fx, f1 = (int)fy, f2 = (int)fz;
        int c0 = (int)ceilf(ix), c1 = (int)ceilf(iy), c2 = (int)ceilf(iz);

        float t0 = ix - fx, t1 = iy - fy, t2 = iz - fz;
        float u0 = 1.0f - t0, u1 = 1.0f - t1, u2 = 1.0f - t2;

        // EXACT reference corner order and weight pairing (validated R1/R3):
        float w0 = u2*u1*u0, w1 = u2*u1*t0, w2 = u2*t1*u0, w3 = u2*t1*t0;
        float w4 = t2*u1*u0, w5 = t2*u1*t0, w6 = t2*t1*u0, w7 = t2*t1*t0;

        // byte offsets of the 8 corner cells (cell = 28 floats = 112 B)
        int o0 = ((f0 * VNL + f1) * VNL + f2) * 112;
        int o1 = ((c0 * VNL + f1) * VNL + f2) * 112;
        int o2 = ((f0 * VNL + c1) * VNL + f2) * 112;
        int o3 = ((f0 * VNL + f1) * VNL + c2) * 112;
        int o4 = ((f0 * VNL + c1) * VNL + c2) * 112;
        int o5 = ((c0 * VNL + f1) * VNL + c2) * 112;
        int o6 = ((c0 * VNL + c1) * VNL + f2) * 112;
        int o7 = ((c0 * VNL + c1) * VNL + c2) * 112;

        float dx = d[3 * i + 0], dy = d[3 * i + 1], dz = d[3 * i + 2];

        float4* ep = wl + 5 * (size_t)slot;
        ep[0] = make_float4(__int_as_float(i), dx, dy, dz);
        ep[1] = make_float4(w0, w1, w2, w3);
        ep[2] = make_float4(w4, w5, w6, w7);
        ep[3] = make_float4(__int_as_float(o0), __int_as_float(o1),
                            __int_as_float(o2), __int_as_float(o3));
        ep[4] = make_float4(__int_as_float(o4), __int_as_float(o5),
                            __int_as_float(o6), __int_as_float(o7));
    }
}

// ---------------- K2: one wave per point ------------------------------------
__global__ __launch_bounds__(K2_BLK) void wave_gather_kernel(
    const float* __restrict__ voxel,
    float* __restrict__ out,
    const unsigned* __restrict__ cnt,
    const float4* __restrict__ wl,
    int N)
{
    __shared__ __align__(16) float s_feat[K2_WPB][32];

    const int cn = (int)*cnt;
    const int wid  = threadIdx.x >> 6;
    const int lane = threadIdx.x & 63;
    const int wave_base = blockIdx.x * K2_WPB + wid;
    const int iters = (cn + K2_WAVES - 1) / K2_WAVES;  // uniform across block

    const int j  = lane >> 3;            // corner 0..7
    const int q  = lane & 7;             // quad 0..7 (7 = idle dup)
    const int q6 = (q < 7) ? q : 6;

    for (int it = 0; it < iters; ++it) {
        int t = wave_base + it * K2_WAVES;
        bool active = t < cn;
        float4 meta = make_float4(0.f, 0.f, 0.f, 0.f);

        if (active) {
            const char* ep = (const char*)(wl + 5 * (size_t)t);
            meta = *(const float4*)ep;                           // broadcast
            float wj = *(const float*)(ep + 16 + 4 * j);         // w[j]
            int  off = *(const int*)  (ep + 48 + 4 * j);         // byteoff[j]
            float4 v4 = *(const float4*)((const char*)voxel + (size_t)(unsigned)off + 16 * q6);

            float4 val;
            val.x = wj * v4.x; val.y = wj * v4.y;
            val.z = wj * v4.z; val.w = wj * v4.w;

            // sum over 8 corners: butterfly on lane bits 3,4,5
            #pragma unroll
            for (int m = 8; m <= 32; m <<= 1) {
                val.x += __shfl_xor(val.x, m);
                val.y += __shfl_xor(val.y, m);
                val.z += __shfl_xor(val.z, m);
                val.w += __shfl_xor(val.w, m);
            }

            if (lane < 7)  // j==0, q==lane: feat quad q
                *reinterpret_cast<float4*>(&s_feat[wid][4 * lane]) = val;
        }
        __syncthreads();   // (also orders LDS write->read; per-wave slots)

        if (active && lane < 4) {
            // lane 0..2 -> color ch=lane (reads feat[1+9ch .. 9+9ch]);
            // lane 3    -> sigma (reads feat[0..8], uses r0)
            int rb = (lane < 3) ? (1 + 9 * lane) : 0;
            float r0 = s_feat[wid][rb + 0];
            float r1 = s_feat[wid][rb + 1];
            float r2 = s_feat[wid][rb + 2];
            float r3 = s_feat[wid][rb + 3];
            float r4 = s_feat[wid][rb + 4];
            float r5 = s_feat[wid][rb + 5];
            float r6 = s_feat[wid][rb + 6];
            float r7 = s_feat[wid][rb + 7];
            float r8 = s_feat[wid][rb + 8];

            int   i  = __float_as_int(meta.x);
            float dx = meta.y, dy = meta.z, dz = meta.w;

            float b0 = SH_C0f;
            float b1 = -SH_C1f * dy;
            float b2 =  SH_C1f * dz;
            float b3 = -SH_C1f * dx;
            float b4 = C2_0f * dx * dy;
            float b5 = C2_1f * dy * dz;
            float b6 = C2_2f * (2.0f * dz * dz - dx * dx - dy * dy);
            float b7 = C2_3f * dx * dz;
            float b8 = C2_4f * (dx * dx - dy * dy);

            float col = b0 * r0 + b1 * r1 + b2 * r2 + b3 * r3 + b4 * r4
                      + b5 * r5 + b6 * r6 + b7 * r7 + b8 * r8;

            float vout = (lane == 3) ? fmaxf(r0, 0.0f) : col;
            size_t a = (lane < 3) ? ((size_t)3 * i + lane) : ((size_t)3 * N + i);
            out[a] = vout;
        }
        __syncthreads();
    }
}

// ---------------- fallback: validated R1 single-kernel ----------------------
__global__ __launch_bounds__(256) void plen_single_kernel(
    const float* __restrict__ x,
    const float* __restrict__ d,
    const float* __restrict__ voxel,
    float* __restrict__ out,
    int N)
{
    int i = blockIdx.x * blockDim.x + threadIdx.x;
    if (i >= N) return;

    float px = x[3 * i + 0] / 1.5f;
    float py = x[3 * i + 1] / 1.5f;
    float pz = x[3 * i + 2] / 1.5f;
    bool mask = (fabsf(px) < 0.5f) && (fabsf(py) < 0.5f) && (fabsf(pz) < 0.5f);

    float outv[4] = {0.f, 0.f, 0.f, 0.f};
    if (mask) {
        const float step = 2.0f / (float)VNL;
        float ix = fminf(fmaxf(px / step + (float)(VNL / 2), 0.0f), (float)(VNL - 1));
        float iy = fminf(fmaxf(py / step + (float)(VNL / 2), 0.0f), (float)(VNL - 1));
        float iz = fminf(fmaxf(pz / step + (float)(VNL / 2), 0.0f), (float)(VNL - 1));
        float fx = floorf(ix), fy = floorf(iy), fz = floorf(iz);
        int f0 = (int)fx, f1 = (int)fy, f2 = (int)fz;
        int c0 = (int)ceilf(ix), c1 = (int)ceilf(iy), c2 = (int)ceilf(iz);
        float t0 = ix - fx, t1 = iy - fy, t2 = iz - fz;
        float u0 = 1.0f - t0, u1 = 1.0f - t1, u2 = 1.0f - t2;

        float w[8]  = { u2*u1*u0, u2*u1*t0, u2*t1*u0, u2*t1*t0,
                        t2*u1*u0, t2*u1*t0, t2*t1*u0, t2*t1*t0 };
        int  cx[8]  = { f0, c0, f0, f0, f0, c0, c0, c0 };
        int  cy[8]  = { f1, f1, c1, f1, c1, f1, c1, c1 };
        int  cz[8]  = { f2, f2, f2, c2, c2, c2, f2, c2 };

        float feat[28];
        #pragma unroll
        for (int c = 0; c < 28; ++c) feat[c] = 0.0f;
        #pragma unroll
        for (int jj = 0; jj < 8; ++jj) {
            size_t base = ((size_t)(cx[jj] * VNL + cy[jj]) * VNL + cz[jj]) * 28;
            const float4* vp = reinterpret_cast<const float4*>(voxel + base);
            float wj = w[jj];
            #pragma unroll
            for (int qq = 0; qq < 7; ++qq) {
                float4 v4 = vp[qq];
                feat[4 * qq + 0] += wj * v4.x;
                feat[4 * qq + 1] += wj * v4.y;
                feat[4 * qq + 2] += wj * v4.z;
                feat[4 * qq + 3] += wj * v4.w;
            }
        }

        float dx = d[3 * i + 0], dy = d[3 * i + 1], dz = d[3 * i + 2];
        float xy = dx * dy, yz = dy * dz, xz = dx * dz;
        float zsq = 2.0f * dz * dz - dx * dx - dy * dy;
        float xmy = dx * dx - dy * dy;
        #pragma unroll
        for (int ch = 0; ch < 3; ++ch) {
            const int bb = 1 + 9 * ch;
            outv[ch] = SH_C0f * feat[bb + 0] - SH_C1f * dy * feat[bb + 1]
                     + SH_C1f * dz * feat[bb + 2] - SH_C1f * dx * feat[bb + 3]
                     + C2_0f * xy  * feat[bb + 4] + C2_1f * yz * feat[bb + 5]
                     + C2_2f * zsq * feat[bb + 6] + C2_3f * xz * feat[bb + 7]
                     + C2_4f * xmy * feat[bb + 8];
        }
        outv[3] = fmaxf(feat[0], 0.0f);
    }
    out[3 * i + 0] = outv[0];
    out[3 * i + 1] = outv[1];
    out[3 * i + 2] = outv[2];
    out[(size_t)3 * N + i] = outv[3];
}

extern "C" void kernel_launch(void* const* d_in, const int* in_sizes, int n_in,
                              void* d_out, int out_size, void* d_ws, size_t ws_size,
                              hipStream_t stream) {
    const float* x     = (const float*)d_in[0];
    const float* d     = (const float*)d_in[1];
    const float* voxel = (const float*)d_in[2];
    float* out = (float*)d_out;
    int N = in_sizes[0] / 3;

    size_t need = 256 + (size_t)N * 80;
    if (ws_size >= need) {
        unsigned* cnt = (unsigned*)d_ws;
        float4* wl = (float4*)((char*)d_ws + 256);

        zero_counter_kernel<<<1, 1, 0, stream>>>(cnt);
        int grid1 = (N + K1_BLK - 1) / K1_BLK;
        mask_expand_kernel<<<grid1, K1_BLK, 0, stream>>>(x, d, out, cnt, wl, N);
        wave_gather_kernel<<<K2_GRID, K2_BLK, 0, stream>>>(voxel, out, cnt, wl, N);
    } else {
        int grid = (N + 255) / 256;
        plen_single_kernel<<<grid, 256, 0, stream>>>(x, d, voxel, out, N);
    }
}

// Round 5
// 66.501 us; speedup vs baseline: 3.9270x; 1.0843x over previous
//
#include <hip/hip_runtime.h>

// Plenoxels: trilinear voxel interp (192^3 x 28 ch) + SH deg-2 eval.
// R5: 8-lanes-per-point gather, SH-before-reduce.
//   lane = (group g = lane>>3, corner j = lane&7); lane j loads corner j's
//   28 floats (7 dwordx4, all 64 lanes active). Each lane computes per-corner
//   partial SH (col = sum_j w_j * (basis . v_j)), then reduce only 4 scalars
//   over lane bits 1/2/4 (12 shfl_xor per 8 points). No LDS, no barriers,
//   8 points per wave-iteration.
// K1 (validated R4): mask + block-aggregated compact into 80B records.

#define VNL 192
#define K1_BLK 1024
#define K2_GRID 2048
#define K2_BLK 256

#define SH_C0f 0.28209479177387814f
#define SH_C1f 0.4886025119029199f
#define C2_0f  1.0925484305920792f
#define C2_1f (-1.0925484305920792f)
#define C2_2f  0.31539156525252005f
#define C2_3f (-1.0925484305920792f)
#define C2_4f  0.5462742152960396f

// ---------------- K0: zero the worklist counter -----------------------------
__global__ void zero_counter_kernel(unsigned* __restrict__ cnt) {
    *cnt = 0;
}

// ---------------- K1: zero out + mask + expand to 80B records ---------------
__global__ __launch_bounds__(K1_BLK) void mask_expand_kernel(
    const float* __restrict__ x,
    const float* __restrict__ d,
    float* __restrict__ out,          // 4N floats, zeroed here
    unsigned* __restrict__ cnt,
    float4* __restrict__ wl,          // 5 float4 per record
    int N)
{
    __shared__ unsigned s_wcnt[K1_BLK / 64];
    __shared__ unsigned s_base;

    int i = blockIdx.x * K1_BLK + threadIdx.x;
    int wid  = threadIdx.x >> 6;
    int lane = threadIdx.x & 63;

    bool act = false;
    float px = 0.f, py = 0.f, pz = 0.f;
    if (i < N) {
        reinterpret_cast<float4*>(out)[i] = make_float4(0.f, 0.f, 0.f, 0.f);
        px = x[3 * i + 0] / 1.5f;
        py = x[3 * i + 1] / 1.5f;
        pz = x[3 * i + 2] / 1.5f;
        act = (fabsf(px) < 0.5f) && (fabsf(py) < 0.5f) && (fabsf(pz) < 0.5f);
    }

    unsigned long long b = __ballot(act);
    unsigned wtot = (unsigned)__popcll(b);
    unsigned pre  = (unsigned)__popcll(b & ((1ull << lane) - 1ull));

    if (lane == 0) s_wcnt[wid] = wtot;
    __syncthreads();
    if (threadIdx.x == 0) {
        unsigned tot = 0;
        #pragma unroll
        for (int ww = 0; ww < K1_BLK / 64; ++ww) tot += s_wcnt[ww];
        s_base = (tot > 0) ? atomicAdd(cnt, tot) : 0u;  // ONE atomic per block
    }
    __syncthreads();

    if (act) {
        unsigned off = s_base;
        for (int ww = 0; ww < wid; ++ww) off += s_wcnt[ww];
        unsigned slot = off + pre;

        const float step = 2.0f / (float)VNL;
        float ix = fminf(fmaxf(px / step + (float)(VNL / 2), 0.0f), (float)(VNL - 1));
        float iy = fminf(fmaxf(py / step + (float)(VNL / 2), 0.0f), (float)(VNL - 1));
        float iz = fminf(fmaxf(pz / step + (float)(VNL / 2), 0.0f), (float)(VNL - 1));

        float fx = floorf(ix), fy = floorf(iy), fz = floorf(iz);
        int f0 = (int)fx, f1 = (int)fy, f2 = (int)fz;
        int c0 = (int)ceilf(ix), c1 = (int)ceilf(iy), c2 = (int)ceilf(iz);

        float t0 = ix - fx, t1 = iy - fy, t2 = iz - fz;
        float u0 = 1.0f - t0, u1 = 1.0f - t1, u2 = 1.0f - t2;

        // EXACT reference corner order and weight pairing (validated R1/R3/R4):
        float w0 = u2*u1*u0, w1 = u2*u1*t0, w2 = u2*t1*u0, w3 = u2*t1*t0;
        float w4 = t2*u1*u0, w5 = t2*u1*t0, w6 = t2*t1*u0, w7 = t2*t1*t0;

        // byte offsets of the 8 corner cells (cell = 28 floats = 112 B)
        int o0 = ((f0 * VNL + f1) * VNL + f2) * 112;
        int o1 = ((c0 * VNL + f1) * VNL + f2) * 112;
        int o2 = ((f0 * VNL + c1) * VNL + f2) * 112;
        int o3 = ((f0 * VNL + f1) * VNL + c2) * 112;
        int o4 = ((f0 * VNL + c1) * VNL + c2) * 112;
        int o5 = ((c0 * VNL + f1) * VNL + c2) * 112;
        int o6 = ((c0 * VNL + c1) * VNL + f2) * 112;
        int o7 = ((c0 * VNL + c1) * VNL + c2) * 112;

        float dx = d[3 * i + 0], dy = d[3 * i + 1], dz = d[3 * i + 2];

        float4* ep = wl + 5 * (size_t)slot;
        ep[0] = make_float4(__int_as_float(i), dx, dy, dz);
        ep[1] = make_float4(w0, w1, w2, w3);
        ep[2] = make_float4(w4, w5, w6, w7);
        ep[3] = make_float4(__int_as_float(o0), __int_as_float(o1),
                            __int_as_float(o2), __int_as_float(o3));
        ep[4] = make_float4(__int_as_float(o4), __int_as_float(o5),
                            __int_as_float(o6), __int_as_float(o7));
    }
}

// ---------------- K2: 8 lanes per point, SH-before-reduce -------------------
__global__ __launch_bounds__(K2_BLK) void group_gather_kernel(
    const float* __restrict__ voxel,
    float* __restrict__ out,
    const unsigned* __restrict__ cnt,
    const float4* __restrict__ wl,
    int N)
{
    const int cn = (int)*cnt;
    const int wave = (blockIdx.x * K2_BLK + threadIdx.x) >> 6;  // global wave id
    const int lane = threadIdx.x & 63;
    const int g = lane >> 3;          // group 0..7 (point within wave-iter)
    const int j = lane & 7;           // corner 0..7
    const int stride = (K2_GRID * K2_BLK / 64) * 8;             // points/sweep

    for (int tb = wave * 8; tb < cn; tb += stride) {
        int t = tb + g;
        bool active = (t < cn);
        int tc = active ? t : (cn - 1);     // clamp: all reads stay in-bounds

        const float* ep = (const float*)(wl + 5 * (size_t)tc);
        float4 meta = *(const float4*)ep;          // (i, dx, dy, dz) broadcast
        float wj  = ep[4 + j];                     // w[j]   (coalesced dwords)
        int   off = ((const int*)ep)[12 + j];      // byteoff[j]

        const char* cell = (const char*)voxel + (size_t)(unsigned)off;
        float4 v0 = *(const float4*)(cell +  0);
        float4 v1 = *(const float4*)(cell + 16);
        float4 v2 = *(const float4*)(cell + 32);
        float4 v3 = *(const float4*)(cell + 48);
        float4 v4 = *(const float4*)(cell + 64);
        float4 v5 = *(const float4*)(cell + 80);
        float4 v6 = *(const float4*)(cell + 96);

        // per-corner partial SH: col_ch_j = w_j * (basis . v_j[1+9ch .. 9+9ch])
        float dx = meta.y, dy = meta.z, dz = meta.w;
        float b1 = -SH_C1f * dy;
        float b2 =  SH_C1f * dz;
        float b3 = -SH_C1f * dx;
        float b4 = C2_0f * dx * dy;
        float b5 = C2_1f * dy * dz;
        float b6 = C2_2f * (2.0f * dz * dz - dx * dx - dy * dy);
        float b7 = C2_3f * dx * dz;
        float b8 = C2_4f * (dx * dx - dy * dy);

        float c0 = SH_C0f*v0.y + b1*v0.z + b2*v0.w + b3*v1.x + b4*v1.y
                 + b5*v1.z + b6*v1.w + b7*v2.x + b8*v2.y;
        float c1 = SH_C0f*v2.z + b1*v2.w + b2*v3.x + b3*v3.y + b4*v3.z
                 + b5*v3.w + b6*v4.x + b7*v4.y + b8*v4.z;
        float c2 = SH_C0f*v4.w + b1*v5.x + b2*v5.y + b3*v5.z + b4*v5.w
                 + b5*v6.x + b6*v6.y + b7*v6.z + b8*v6.w;
        c0 *= wj; c1 *= wj; c2 *= wj;
        float f0 = wj * v0.x;               // feat[0] partial (sum BEFORE relu)

        // reduce 4 scalars over corner bits (stays within the 8-lane group)
        #pragma unroll
        for (int m = 1; m <= 4; m <<= 1) {
            c0 += __shfl_xor(c0, m);
            c1 += __shfl_xor(c1, m);
            c2 += __shfl_xor(c2, m);
            f0 += __shfl_xor(f0, m);
        }

        if (active && j < 4) {
            int i = __float_as_int(meta.x);
            float r = (j == 0) ? c0 : (j == 1) ? c1 : (j == 2) ? c2
                                                    : fmaxf(f0, 0.0f);
            size_t a = (j < 3) ? ((size_t)3 * i + j) : ((size_t)3 * N + i);
            out[a] = r;
        }
    }
}

// ---------------- fallback: validated R1 single-kernel ----------------------
__global__ __launch_bounds__(256) void plen_single_kernel(
    const float* __restrict__ x,
    const float* __restrict__ d,
    const float* __restrict__ voxel,
    float* __restrict__ out,
    int N)
{
    int i = blockIdx.x * blockDim.x + threadIdx.x;
    if (i >= N) return;

    float px = x[3 * i + 0] / 1.5f;
    float py = x[3 * i + 1] / 1.5f;
    float pz = x[3 * i + 2] / 1.5f;
    bool mask = (fabsf(px) < 0.5f) && (fabsf(py) < 0.5f) && (fabsf(pz) < 0.5f);

    float outv[4] = {0.f, 0.f, 0.f, 0.f};
    if (mask) {
        const float step = 2.0f / (float)VNL;
        float ix = fminf(fmaxf(px / step + (float)(VNL / 2), 0.0f), (float)(VNL - 1));
        float iy = fminf(fmaxf(py / step + (float)(VNL / 2), 0.0f), (float)(VNL - 1));
        float iz = fminf(fmaxf(pz / step + (float)(VNL / 2), 0.0f), (float)(VNL - 1));
        float fx = floorf(ix), fy = floorf(iy), fz = floorf(iz);
        int f0 = (int)fx, f1 = (int)fy, f2 = (int)fz;
        int c0 = (int)ceilf(ix), c1 = (int)ceilf(iy), c2 = (int)ceilf(iz);
        float t0 = ix - fx, t1 = iy - fy, t2 = iz - fz;
        float u0 = 1.0f - t0, u1 = 1.0f - t1, u2 = 1.0f - t2;

        float w[8]  = { u2*u1*u0, u2*u1*t0, u2*t1*u0, u2*t1*t0,
                        t2*u1*u0, t2*u1*t0, t2*t1*u0, t2*t1*t0 };
        int  cx[8]  = { f0, c0, f0, f0, f0, c0, c0, c0 };
        int  cy[8]  = { f1, f1, c1, f1, c1, f1, c1, c1 };
        int  cz[8]  = { f2, f2, f2, c2, c2, c2, f2, c2 };

        float feat[28];
        #pragma unroll
        for (int c = 0; c < 28; ++c) feat[c] = 0.0f;
        #pragma unroll
        for (int jj = 0; jj < 8; ++jj) {
            size_t base = ((size_t)(cx[jj] * VNL + cy[jj]) * VNL + cz[jj]) * 28;
            const float4* vp = reinterpret_cast<const float4*>(voxel + base);
            float wjv = w[jj];
            #pragma unroll
            for (int qq = 0; qq < 7; ++qq) {
                float4 v4 = vp[qq];
                feat[4 * qq + 0] += wjv * v4.x;
                feat[4 * qq + 1] += wjv * v4.y;
                feat[4 * qq + 2] += wjv * v4.z;
                feat[4 * qq + 3] += wjv * v4.w;
            }
        }

        float dx = d[3 * i + 0], dy = d[3 * i + 1], dz = d[3 * i + 2];
        float xy = dx * dy, yz = dy * dz, xz = dx * dz;
        float zsq = 2.0f * dz * dz - dx * dx - dy * dy;
        float xmy = dx * dx - dy * dy;
        #pragma unroll
        for (int ch = 0; ch < 3; ++ch) {
            const int bb = 1 + 9 * ch;
            outv[ch] = SH_C0f * feat[bb + 0] - SH_C1f * dy * feat[bb + 1]
                     + SH_C1f * dz * feat[bb + 2] - SH_C1f * dx * feat[bb + 3]
                     + C2_0f * xy  * feat[bb + 4] + C2_1f * yz * feat[bb + 5]
                     + C2_2f * zsq * feat[bb + 6] + C2_3f * xz * feat[bb + 7]
                     + C2_4f * xmy * feat[bb + 8];
        }
        outv[3] = fmaxf(feat[0], 0.0f);
    }
    out[3 * i + 0] = outv[0];
    out[3 * i + 1] = outv[1];
    out[3 * i + 2] = outv[2];
    out[(size_t)3 * N + i] = outv[3];
}

extern "C" void kernel_launch(void* const* d_in, const int* in_sizes, int n_in,
                              void* d_out, int out_size, void* d_ws, size_t ws_size,
                              hipStream_t stream) {
    const float* x     = (const float*)d_in[0];
    const float* d     = (const float*)d_in[1];
    const float* voxel = (const float*)d_in[2];
    float* out = (float*)d_out;
    int N = in_sizes[0] / 3;

    size_t need = 256 + (size_t)N * 80;
    if (ws_size >= need) {
        unsigned* cnt = (unsigned*)d_ws;
        float4* wl = (float4*)((char*)d_ws + 256);

        zero_counter_kernel<<<1, 1, 0, stream>>>(cnt);
        int grid1 = (N + K1_BLK - 1) / K1_BLK;
        mask_expand_kernel<<<grid1, K1_BLK, 0, stream>>>(x, d, out, cnt, wl, N);
        group_gather_kernel<<<K2_GRID, K2_BLK, 0, stream>>>(voxel, out, cnt, wl, N);
    } else {
        int grid = (N + 255) / 256;
        plen_single_kernel<<<grid, 256, 0, stream>>>(x, d, voxel, out, N);
    }
}

// Round 6
// 49.263 us; speedup vs baseline: 5.3012x; 1.3499x over previous
//
#include <hip/hip_runtime.h>

// Plenoxels: trilinear voxel interp (192^3 x 28 ch) + SH deg-2 eval.
// R6: single fused kernel. R3/R4/R5 K2 restructures gave 89/72/66.5us ->
// gather no longer dominant; the 3-dispatch pipeline (launch overhead, 27MB
// worklist round-trip, counter serialization) is. Fuse: each wave masks its
// 64 points, zeroes inactive outputs, then gathers its ~10 active points in
// chunks of 8 using the validated 8-lanes-per-corner + SH-before-reduce
// structure (R5). Owner data via full-exec shfl; weights/offsets recomputed
// per-lane from broadcast (px,py,pz). Group-granular exec (all 8 lanes of a
// group share rank r) keeps the shfl_xor reduce safe under divergence.

#define VNL 192

#define SH_C0f 0.28209479177387814f
#define SH_C1f 0.4886025119029199f
#define C2_0f  1.0925484305920792f
#define C2_1f (-1.0925484305920792f)
#define C2_2f  0.31539156525252005f
#define C2_3f (-1.0925484305920792f)
#define C2_4f  0.5462742152960396f

__global__ __launch_bounds__(256) void plen_fused_kernel(
    const float* __restrict__ x,
    const float* __restrict__ d,
    const float* __restrict__ voxel,
    float* __restrict__ out,
    int N)
{
    int i = blockIdx.x * 256 + threadIdx.x;
    const int lane = threadIdx.x & 63;
    const int g = lane >> 3;   // group 0..7 (point slot within chunk)
    const int j = lane & 7;    // corner 0..7

    bool act = false;
    float px = 0.f, py = 0.f, pz = 0.f;
    float vdx = 0.f, vdy = 0.f, vdz = 0.f;
    if (i < N) {
        px = x[3 * i + 0] / 1.5f;
        py = x[3 * i + 1] / 1.5f;
        pz = x[3 * i + 2] / 1.5f;
        act = (fabsf(px) < 0.5f) && (fabsf(py) < 0.5f) && (fabsf(pz) < 0.5f);
        vdx = d[3 * i + 0];
        vdy = d[3 * i + 1];
        vdz = d[3 * i + 2];
        if (!act) {
            // This thread's own outputs are zero; active outputs are written
            // below by the gather phase (disjoint -> no race).
            out[3 * i + 0] = 0.f;
            out[3 * i + 1] = 0.f;
            out[3 * i + 2] = 0.f;
            out[(size_t)3 * N + i] = 0.f;
        }
    }

    unsigned long long bal = __ballot(act);
    int nact = (int)__popcll(bal);

    for (int c = 0; c * 8 < nact; ++c) {
        int r = c * 8 + g;              // rank of this group's point
        bool gact = (r < nact);         // uniform across the 8-lane group
        int rr = gact ? r : 0;

        // owner = lane index of the rr-th set bit of bal (nact>0 here)
        unsigned long long m = bal;
        for (int k = 0; k < rr; ++k) m &= (m - 1);
        int owner = (int)__builtin_ctzll(m);

        // Broadcast the point's data from its owner lane (FULL exec: owner
        // may sit in a lane whose group is inactive this chunk).
        float ppx = __shfl(px,  owner);
        float ppy = __shfl(py,  owner);
        float ppz = __shfl(pz,  owner);
        float pdx = __shfl(vdx, owner);
        float pdy = __shfl(vdy, owner);
        float pdz = __shfl(vdz, owner);
        int   pi  = __shfl(i,   owner);

        if (gact) {
            // ---- per-lane index/weight math (exact validated semantics) ----
            const float step = 2.0f / (float)VNL;
            float ix = fminf(fmaxf(ppx / step + (float)(VNL / 2), 0.0f), (float)(VNL - 1));
            float iy = fminf(fmaxf(ppy / step + (float)(VNL / 2), 0.0f), (float)(VNL - 1));
            float iz = fminf(fmaxf(ppz / step + (float)(VNL / 2), 0.0f), (float)(VNL - 1));

            float fx = floorf(ix), fy = floorf(iy), fz = floorf(iz);
            int f0 = (int)fx, f1 = (int)fy, f2 = (int)fz;
            int c0i = (int)ceilf(ix), c1i = (int)ceilf(iy), c2i = (int)ceilf(iz);

            float t0 = ix - fx, t1 = iy - fy, t2 = iz - fz;
            float u0 = 1.0f - t0, u1 = 1.0f - t1, u2 = 1.0f - t2;

            // w[j] = (j&4?t2:u2)*(j&2?t1:u1)*(j&1?t0:u0)  -- matches ref table
            float wj = ((j & 4) ? t2 : u2) * ((j & 2) ? t1 : u1) * ((j & 1) ? t0 : u0);

            // Reference's NON-standard corner tables:
            //   cx c0 at j in {1,5,6,7} -> 0xE2 ; cy c1 at {2,4,6,7} -> 0xD4 ;
            //   cz c2 at {3,4,5,7} -> 0xB8
            int X = ((0xE2 >> j) & 1) ? c0i : f0;
            int Y = ((0xD4 >> j) & 1) ? c1i : f1;
            int Z = ((0xB8 >> j) & 1) ? c2i : f2;
            int off = ((X * VNL + Y) * VNL + Z) * 112;   // cell = 28 f32 = 112 B

            const char* cell = (const char*)voxel + (size_t)(unsigned)off;
            float4 v0 = *(const float4*)(cell +  0);
            float4 v1 = *(const float4*)(cell + 16);
            float4 v2 = *(const float4*)(cell + 32);
            float4 v3 = *(const float4*)(cell + 48);
            float4 v4 = *(const float4*)(cell + 64);
            float4 v5 = *(const float4*)(cell + 80);
            float4 v6 = *(const float4*)(cell + 96);

            // ---- per-corner partial SH (col = sum_j w_j * (basis . v_j)) ----
            float b1 = -SH_C1f * pdy;
            float b2 =  SH_C1f * pdz;
            float b3 = -SH_C1f * pdx;
            float b4 = C2_0f * pdx * pdy;
            float b5 = C2_1f * pdy * pdz;
            float b6 = C2_2f * (2.0f * pdz * pdz - pdx * pdx - pdy * pdy);
            float b7 = C2_3f * pdx * pdz;
            float b8 = C2_4f * (pdx * pdx - pdy * pdy);

            float cc0 = SH_C0f*v0.y + b1*v0.z + b2*v0.w + b3*v1.x + b4*v1.y
                      + b5*v1.z + b6*v1.w + b7*v2.x + b8*v2.y;
            float cc1 = SH_C0f*v2.z + b1*v2.w + b2*v3.x + b3*v3.y + b4*v3.z
                      + b5*v3.w + b6*v4.x + b7*v4.y + b8*v4.z;
            float cc2 = SH_C0f*v4.w + b1*v5.x + b2*v5.y + b3*v5.z + b4*v5.w
                      + b5*v6.x + b6*v6.y + b7*v6.z + b8*v6.w;
            cc0 *= wj; cc1 *= wj; cc2 *= wj;
            float ff0 = wj * v0.x;          // feat[0] partial (sum BEFORE relu)

            // ---- reduce 4 scalars over corner bits (within 8-lane group) ----
            #pragma unroll
            for (int mm = 1; mm <= 4; mm <<= 1) {
                cc0 += __shfl_xor(cc0, mm);
                cc1 += __shfl_xor(cc1, mm);
                cc2 += __shfl_xor(cc2, mm);
                ff0 += __shfl_xor(ff0, mm);
            }

            if (j < 4) {
                float rv = (j == 0) ? cc0 : (j == 1) ? cc1 : (j == 2) ? cc2
                                                          : fmaxf(ff0, 0.0f);
                size_t a = (j < 3) ? ((size_t)3 * pi + j) : ((size_t)3 * N + pi);
                out[a] = rv;
            }
        }
    }
}

extern "C" void kernel_launch(void* const* d_in, const int* in_sizes, int n_in,
                              void* d_out, int out_size, void* d_ws, size_t ws_size,
                              hipStream_t stream) {
    const float* x     = (const float*)d_in[0];
    const float* d     = (const float*)d_in[1];
    const float* voxel = (const float*)d_in[2];
    float* out = (float*)d_out;
    int N = in_sizes[0] / 3;

    int grid = (N + 255) / 256;
    plen_fused_kernel<<<grid, 256, 0, stream>>>(x, d, voxel, out, N);
}

// Round 8
// 47.652 us; speedup vs baseline: 5.4803x; 1.0338x over previous
//
#include <hip/hip_runtime.h>

// Plenoxels: trilinear voxel interp (192^3 x 28 ch) + SH deg-2 eval.
// R8 = R7 with the DPP builtin fixed (ctrl must be a compile-time constant ->
// template parameter).
//  - block pools its ~42 active records (32B each) in LDS: ballot -> per-wave
//    counts -> prefix -> active lanes write; ONE barrier.
//  - waves take chunks of 8 records strided (c = wid, wid+4, ...): group g
//    reads record c*8+g via 2x ds_read_b128 at group-uniform addr (LDS
//    broadcast) -- kills owner-find loop + 7 ds_bpermute per chunk.
//  - corner reduce via DPP adds (quad_perm xor1/xor2 + row_half_mirror)
//    instead of 12 ds_bpermute shuffles.
// Gather / SH math identical to validated R6.

#define VNL 192
#define BLK 256
#define WPB 4

#define SH_C0f 0.28209479177387814f
#define SH_C1f 0.4886025119029199f
#define C2_0f  1.0925484305920792f
#define C2_1f (-1.0925484305920792f)
#define C2_2f  0.31539156525252005f
#define C2_3f (-1.0925484305920792f)
#define C2_4f  0.5462742152960396f

template <int CTRL>
__device__ __forceinline__ float dpp_add(float v) {
    int s = __builtin_amdgcn_update_dpp(0, __float_as_int(v), CTRL, 0xF, 0xF, true);
    return v + __int_as_float(s);
}

__global__ __launch_bounds__(BLK) void plen_fused_kernel(
    const float* __restrict__ x,
    const float* __restrict__ d,
    const float* __restrict__ voxel,
    float* __restrict__ out,
    int N)
{
    __shared__ __align__(16) float s_pool[BLK][8];   // 8KB: pooled records
    __shared__ unsigned s_wcnt[WPB];

    const int tid  = threadIdx.x;
    const int i    = blockIdx.x * BLK + tid;
    const int wid  = tid >> 6;
    const int lane = tid & 63;
    const int g = lane >> 3;   // group 0..7 (record slot within chunk)
    const int j = lane & 7;    // corner 0..7

    // ---- phase 1: mask, zero inactive outputs, pool active records --------
    bool act = false;
    float px = 0.f, py = 0.f, pz = 0.f;
    float vdx = 0.f, vdy = 0.f, vdz = 0.f;
    if (i < N) {
        px = x[3 * i + 0] / 1.5f;
        py = x[3 * i + 1] / 1.5f;
        pz = x[3 * i + 2] / 1.5f;
        act = (fabsf(px) < 0.5f) && (fabsf(py) < 0.5f) && (fabsf(pz) < 0.5f);
        vdx = d[3 * i + 0];
        vdy = d[3 * i + 1];
        vdz = d[3 * i + 2];
        if (!act) {
            out[3 * i + 0] = 0.f;
            out[3 * i + 1] = 0.f;
            out[3 * i + 2] = 0.f;
            out[(size_t)3 * N + i] = 0.f;
        }
    }

    unsigned long long bal = __ballot(act);
    unsigned wtot = (unsigned)__popcll(bal);
    unsigned pre  = (unsigned)__popcll(bal & ((1ull << lane) - 1ull));
    if (lane == 0) s_wcnt[wid] = wtot;
    __syncthreads();

    unsigned n0 = s_wcnt[0], n1 = s_wcnt[1], n2 = s_wcnt[2], n3 = s_wcnt[3];
    unsigned M = n0 + n1 + n2 + n3;
    unsigned base = (wid > 0 ? n0 : 0u) + (wid > 1 ? n1 : 0u) + (wid > 2 ? n2 : 0u);

    if (act) {
        unsigned slot = base + pre;
        float4* rp = reinterpret_cast<float4*>(&s_pool[slot][0]);
        rp[0] = make_float4(px, py, pz, __int_as_float(i));
        rp[1] = make_float4(vdx, vdy, vdz, 0.f);
    }
    __syncthreads();

    // ---- phase 2: waves consume chunks of 8 records (strided) -------------
    for (unsigned c = (unsigned)wid; c * 8u < M; c += WPB) {
        unsigned r = c * 8u + (unsigned)g;
        bool gact = (r < M);                 // uniform across 8-lane group
        unsigned rr = gact ? r : 0u;

        const float4* rp = reinterpret_cast<const float4*>(&s_pool[rr][0]);
        float4 e0 = rp[0];                   // (px,py,pz,i)  LDS broadcast
        float4 e1 = rp[1];                   // (dx,dy,dz,-)

        if (gact) {
            float ppx = e0.x, ppy = e0.y, ppz = e0.z;
            int   pi  = __float_as_int(e0.w);
            float pdx = e1.x, pdy = e1.y, pdz = e1.z;

            // ---- per-lane index/weight math (exact validated semantics) ----
            const float step = 2.0f / (float)VNL;
            float ix = fminf(fmaxf(ppx / step + (float)(VNL / 2), 0.0f), (float)(VNL - 1));
            float iy = fminf(fmaxf(ppy / step + (float)(VNL / 2), 0.0f), (float)(VNL - 1));
            float iz = fminf(fmaxf(ppz / step + (float)(VNL / 2), 0.0f), (float)(VNL - 1));

            float fx = floorf(ix), fy = floorf(iy), fz = floorf(iz);
            int f0 = (int)fx, f1 = (int)fy, f2 = (int)fz;
            int c0i = (int)ceilf(ix), c1i = (int)ceilf(iy), c2i = (int)ceilf(iz);

            float t0 = ix - fx, t1 = iy - fy, t2 = iz - fz;
            float u0 = 1.0f - t0, u1 = 1.0f - t1, u2 = 1.0f - t2;

            // w[j] matches the reference weight table (validated R6)
            float wj = ((j & 4) ? t2 : u2) * ((j & 2) ? t1 : u1) * ((j & 1) ? t0 : u0);

            // Reference's NON-standard corner tables (validated R6):
            int X = ((0xE2 >> j) & 1) ? c0i : f0;
            int Y = ((0xD4 >> j) & 1) ? c1i : f1;
            int Z = ((0xB8 >> j) & 1) ? c2i : f2;
            int off = ((X * VNL + Y) * VNL + Z) * 112;   // cell = 28 f32 = 112 B

            const char* cell = (const char*)voxel + (size_t)(unsigned)off;
            float4 v0 = *(const float4*)(cell +  0);
            float4 v1 = *(const float4*)(cell + 16);
            float4 v2 = *(const float4*)(cell + 32);
            float4 v3 = *(const float4*)(cell + 48);
            float4 v4 = *(const float4*)(cell + 64);
            float4 v5 = *(const float4*)(cell + 80);
            float4 v6 = *(const float4*)(cell + 96);

            // ---- per-corner partial SH (validated R5/R6 channel mapping) ----
            float b1 = -SH_C1f * pdy;
            float b2 =  SH_C1f * pdz;
            float b3 = -SH_C1f * pdx;
            float b4 = C2_0f * pdx * pdy;
            float b5 = C2_1f * pdy * pdz;
            float b6 = C2_2f * (2.0f * pdz * pdz - pdx * pdx - pdy * pdy);
            float b7 = C2_3f * pdx * pdz;
            float b8 = C2_4f * (pdx * pdx - pdy * pdy);

            float cc0 = SH_C0f*v0.y + b1*v0.z + b2*v0.w + b3*v1.x + b4*v1.y
                      + b5*v1.z + b6*v1.w + b7*v2.x + b8*v2.y;
            float cc1 = SH_C0f*v2.z + b1*v2.w + b2*v3.x + b3*v3.y + b4*v3.z
                      + b5*v3.w + b6*v4.x + b7*v4.y + b8*v4.z;
            float cc2 = SH_C0f*v4.w + b1*v5.x + b2*v5.y + b3*v5.z + b4*v5.w
                      + b5*v6.x + b6*v6.y + b7*v6.z + b8*v6.w;
            cc0 *= wj; cc1 *= wj; cc2 *= wj;
            float ff0 = wj * v0.x;          // feat[0] partial (sum BEFORE relu)

            // ---- corner reduce via DPP (within each 8-lane group) ----------
            // xor1 = quad_perm[1,0,3,2] (0xB1); xor2 = quad_perm[2,3,0,1] (0x4E);
            // cross-half = ROW_HALF_MIRROR (0x141). All stay inside the group.
            cc0 = dpp_add<0xB1>(cc0); cc1 = dpp_add<0xB1>(cc1);
            cc2 = dpp_add<0xB1>(cc2); ff0 = dpp_add<0xB1>(ff0);
            cc0 = dpp_add<0x4E>(cc0); cc1 = dpp_add<0x4E>(cc1);
            cc2 = dpp_add<0x4E>(cc2); ff0 = dpp_add<0x4E>(ff0);
            cc0 = dpp_add<0x141>(cc0); cc1 = dpp_add<0x141>(cc1);
            cc2 = dpp_add<0x141>(cc2); ff0 = dpp_add<0x141>(ff0);

            if (j < 4) {
                float rv = (j == 0) ? cc0 : (j == 1) ? cc1 : (j == 2) ? cc2
                                                          : fmaxf(ff0, 0.0f);
                size_t a = (j < 3) ? ((size_t)3 * pi + j) : ((size_t)3 * N + pi);
                out[a] = rv;
            }
        }
    }
}

extern "C" void kernel_launch(void* const* d_in, const int* in_sizes, int n_in,
                              void* d_out, int out_size, void* d_ws, size_t ws_size,
                              hipStream_t stream) {
    const float* x     = (const float*)d_in[0];
    const float* d     = (const float*)d_in[1];
    const float* voxel = (const float*)d_in[2];
    float* out = (float*)d_out;
    int N = in_sizes[0] / 3;

    int grid = (N + BLK - 1) / BLK;
    plen_fused_kernel<<<grid, BLK, 0, stream>>>(x, d, voxel, out, N);
}